// Round 1
// baseline (128.357 us; speedup 1.0000x reference)
//
#include <hip/hip_runtime.h>
#include <math.h>

#define HID 20
#define NGATE 80
#define NLAYER 2

__device__ __forceinline__ float sigmoidf_(float v) { return 1.0f / (1.0f + expf(-v)); }

// Build lookup table of the scalar->scalar network: tbl[i] = (theta(x_i), act(x_i)).
// Exact fp32 reference math; perf-irrelevant (16K evaluations total).
__global__ void build_table_kernel(
    const float* __restrict__ W1, const float* __restrict__ b1,
    const float* __restrict__ W_ih, const float* __restrict__ b_ih,
    const float* __restrict__ b_hh,
    const float* __restrict__ W_out, const float* __restrict__ b_out,
    const float* __restrict__ W_act, const float* __restrict__ b_act,
    float2* __restrict__ tbl, int tblN, float x0, float dx)
{
    int i = blockIdx.x * blockDim.x + threadIdx.x;
    if (i >= tblN) return;
    float xv = x0 + dx * (float)i;

    float h[HID];
#pragma unroll
    for (int k = 0; k < HID; ++k) h[k] = xv * W1[k] + b1[k];

    for (int l = 0; l < NLAYER; ++l) {
        const float* Wl = W_ih + l * (NGATE * HID);
        const float* bi = b_ih + l * NGATE;
        const float* bh = b_hh + l * NGATE;
        float hn[HID];
        for (int gi = 0; gi < HID; ++gi) {
            // torch LSTMCell gate order: i (0..19), f (20..39, unused: c0=0), g (40..59), o (60..79)
            float si = bi[gi]      + bh[gi];
            float sg = bi[40 + gi] + bh[40 + gi];
            float so = bi[60 + gi] + bh[60 + gi];
#pragma unroll
            for (int k = 0; k < HID; ++k) {
                float hk = h[k];
                si = fmaf(Wl[gi * HID + k],        hk, si);
                sg = fmaf(Wl[(40 + gi) * HID + k], hk, sg);
                so = fmaf(Wl[(60 + gi) * HID + k], hk, so);
            }
            float iv = sigmoidf_(si);
            float gv = tanhf(sg);
            float ov = sigmoidf_(so);
            hn[gi] = ov * tanhf(iv * gv);   // c = i*g (f*c0 == 0), h = o*tanh(c)
        }
#pragma unroll
        for (int k = 0; k < HID; ++k) h[k] = hn[k];
    }

    float th = b_out[0];
    float ac = b_act[0];
#pragma unroll
    for (int k = 0; k < HID; ++k) {
        th = fmaf(h[k], W_out[k], th);
        ac = fmaf(h[k], W_act[k], ac);
    }
    tbl[i] = make_float2(th, ac);
}

// Memory-bound gather+lerp: theta[b,p] = lerp(F, x), qt[b] += mean(lerp(G, x)).
// Each block handles 2048 contiguous elements of one row (2 x float4 per thread).
__global__ __launch_bounds__(256) void eval_kernel(
    const float* __restrict__ x, const float2* __restrict__ tbl,
    float* __restrict__ theta, float* __restrict__ qt,
    int tblN, float x0, float inv_dx, int P, int chunks_per_row)
{
    int b = blockIdx.x / chunks_per_row;
    int c = blockIdx.x % chunks_per_row;
    size_t base = (size_t)b * (size_t)P + (size_t)c * 2048;
    const float4* xin = (const float4*)(x + base);
    float4* tout = (float4*)(theta + base);

    float gsum = 0.0f;
    float tmax = (float)(tblN - 1);

#pragma unroll
    for (int j = 0; j < 2; ++j) {
        float4 xv = xin[j * 256 + threadIdx.x];
        float in[4] = {xv.x, xv.y, xv.z, xv.w};
        float o[4];
#pragma unroll
        for (int k = 0; k < 4; ++k) {
            float tt = (in[k] - x0) * inv_dx;
            tt = fminf(fmaxf(tt, 0.0f), tmax);
            int i0 = (int)tt;
            if (i0 > tblN - 2) i0 = tblN - 2;
            float fr = tt - (float)i0;
            float2 a  = tbl[i0];
            float2 bb = tbl[i0 + 1];
            o[k]  = fmaf(fr, bb.x - a.x, a.x);
            gsum += fmaf(fr, bb.y - a.y, a.y);
        }
        tout[j * 256 + threadIdx.x] = make_float4(o[0], o[1], o[2], o[3]);
    }

    // block reduction: wave64 shuffle tree, then 4 wave sums via LDS
#pragma unroll
    for (int off = 32; off > 0; off >>= 1)
        gsum += __shfl_down(gsum, off, 64);
    __shared__ float wsum[4];
    int wid  = threadIdx.x >> 6;
    int lane = threadIdx.x & 63;
    if (lane == 0) wsum[wid] = gsum;
    __syncthreads();
    if (threadIdx.x == 0) {
        float s = wsum[0] + wsum[1] + wsum[2] + wsum[3];
        atomicAdd(&qt[b], s * (1.0f / (float)P));
    }
}

extern "C" void kernel_launch(void* const* d_in, const int* in_sizes, int n_in,
                              void* d_out, int out_size, void* d_ws, size_t ws_size,
                              hipStream_t stream) {
    const float* x     = (const float*)d_in[0];
    const float* W1    = (const float*)d_in[1];
    const float* b1    = (const float*)d_in[2];
    const float* W_ih  = (const float*)d_in[3];
    const float* b_ih  = (const float*)d_in[4];
    // d_in[5] = W_hh: unused (h0 = 0, only b_hh survives)
    const float* b_hh  = (const float*)d_in[6];
    const float* W_out = (const float*)d_in[7];
    const float* b_out = (const float*)d_in[8];
    const float* W_act = (const float*)d_in[9];
    const float* b_act = (const float*)d_in[10];

    int BP = in_sizes[0];          // B*P = 2097152
    int B  = out_size - BP;        // 64 (theta flat + qt)
    int P  = BP / B;               // 32768

    float* theta = (float*)d_out;
    float* qt    = theta + BP;

    // Table in workspace; shrink if ws is small (accuracy headroom is ~4 orders).
    int tblN = 16384;
    while ((size_t)tblN * sizeof(float2) > ws_size && tblN > 64) tblN >>= 1;
    float2* tbl = (float2*)d_ws;

    const float X0 = -10.0f, X1 = 10.0f;
    float dx = (X1 - X0) / (float)(tblN - 1);
    float inv_dx = 1.0f / dx;

    // qt region is re-poisoned before every launch; zero it (capturable memset node)
    hipMemsetAsync(qt, 0, B * sizeof(float), stream);

    build_table_kernel<<<(tblN + 255) / 256, 256, 0, stream>>>(
        W1, b1, W_ih, b_ih, b_hh, W_out, b_out, W_act, b_act, tbl, tblN, X0, dx);

    int chunks = P / 2048;
    eval_kernel<<<B * chunks, 256, 0, stream>>>(
        x, tbl, theta, qt, tblN, X0, inv_dx, P, chunks);
}

// Round 2
// 97.375 us; speedup vs baseline: 1.3182x; 1.3182x over previous
//
#include <hip/hip_runtime.h>
#include <math.h>

#define HID 20
#define NGATE 80
#define NLAYER 2
#define PTS_PER_BLK 12   // 12 points x 20 gates = 240 active threads of 256

__device__ __forceinline__ float sigmoidf_(float v) { return 1.0f / (1.0f + expf(-v)); }

// Cooperative table build: block handles 12 points; thread (p_local, gi) computes
// gate gi of point p_local; hidden state lives in LDS between layers.
// Table format: tbl4[i] = (F_i, G_i, F_{i+1}, G_{i+1}) so eval does ONE 16B gather.
__global__ __launch_bounds__(256) void build_table_kernel(
    const float* __restrict__ W1, const float* __restrict__ b1,
    const float* __restrict__ W_ih, const float* __restrict__ b_ih,
    const float* __restrict__ b_hh,
    const float* __restrict__ W_out, const float* __restrict__ b_out,
    const float* __restrict__ W_act, const float* __restrict__ b_act,
    float* __restrict__ tblf, int tblN, float x0, float dx)
{
    __shared__ float sh[PTS_PER_BLK][HID];

    int tid = threadIdx.x;
    bool active = tid < PTS_PER_BLK * HID;
    int p_local = tid / HID;        // 0..11
    int gi      = tid % HID;        // 0..19
    int i = blockIdx.x * PTS_PER_BLK + p_local;
    bool valid = active && (i < tblN);

    // stage 0: h0[gi] = x*W1[gi] + b1[gi]
    if (active) {
        float xv = x0 + dx * (float)i;
        sh[p_local][gi] = fmaf(xv, W1[gi], b1[gi]);
    }
    __syncthreads();

    float hval = 0.0f;
    for (int l = 0; l < NLAYER; ++l) {
        if (active) {
            const float* Wl = W_ih + l * (NGATE * HID);
            const float* bi = b_ih + l * NGATE;
            const float* bh = b_hh + l * NGATE;
            // torch gate order: i(0..19) f(20..39, dead: c0=0) g(40..59) o(60..79)
            float si = bi[gi]          + bh[gi];
            float sg = bi[HID*2 + gi]  + bh[HID*2 + gi];
            float so = bi[HID*3 + gi]  + bh[HID*3 + gi];
            const float* wi = Wl + gi * HID;
            const float* wg = Wl + (HID*2 + gi) * HID;
            const float* wo = Wl + (HID*3 + gi) * HID;
#pragma unroll
            for (int k = 0; k < HID; ++k) {
                float hk = sh[p_local][k];
                si = fmaf(wi[k], hk, si);
                sg = fmaf(wg[k], hk, sg);
                so = fmaf(wo[k], hk, so);
            }
            float iv = sigmoidf_(si);
            float gv = tanhf(sg);
            float ov = sigmoidf_(so);
            hval = ov * tanhf(iv * gv);   // c = i*g (f*c0 == 0), h = o*tanh(c)
        }
        __syncthreads();
        if (active) sh[p_local][gi] = hval;
        __syncthreads();
    }

    // output: gi==0 -> theta dot, gi==1 -> act dot; write duplicated-neighbor table
    if (valid && gi < 2) {
        const float* Wv = (gi == 0) ? W_out : W_act;
        float acc = (gi == 0) ? b_out[0] : b_act[0];
#pragma unroll
        for (int k = 0; k < HID; ++k) acc = fmaf(sh[p_local][k], Wv[k], acc);
        tblf[4 * i + gi] = acc;                       // (F_i, G_i)
        if (i > 0) tblf[4 * (i - 1) + 2 + gi] = acc;  // neighbor copy (F_i, G_i) -> entry i-1 zw
    }
}

// Memory-bound gather+lerp: theta[b,p] = lerp(F, x), qt[b] += mean(lerp(G, x)).
// Each block handles 2048 contiguous elements of one row (2 x float4 per thread).
__global__ __launch_bounds__(256) void eval_kernel(
    const float* __restrict__ x, const float4* __restrict__ tbl4,
    float* __restrict__ theta, float* __restrict__ qt,
    int tblN, float x0, float inv_dx, int P, int chunks_per_row)
{
    int b = blockIdx.x / chunks_per_row;
    int c = blockIdx.x % chunks_per_row;
    size_t base = (size_t)b * (size_t)P + (size_t)c * 2048;
    const float4* xin = (const float4*)(x + base);
    float4* tout = (float4*)(theta + base);

    float gsum = 0.0f;
    float tmax = (float)(tblN - 1);

#pragma unroll
    for (int j = 0; j < 2; ++j) {
        float4 xv = xin[j * 256 + threadIdx.x];
        float in[4] = {xv.x, xv.y, xv.z, xv.w};
        float o[4];
#pragma unroll
        for (int k = 0; k < 4; ++k) {
            float tt = (in[k] - x0) * inv_dx;
            tt = fminf(fmaxf(tt, 0.0f), tmax);
            int i0 = (int)tt;
            if (i0 > tblN - 2) i0 = tblN - 2;
            float fr = tt - (float)i0;
            float4 e = tbl4[i0];              // (F0, G0, F1, G1) — one 16B gather
            o[k]  = fmaf(fr, e.z - e.x, e.x);
            gsum += fmaf(fr, e.w - e.y, e.y);
        }
        tout[j * 256 + threadIdx.x] = make_float4(o[0], o[1], o[2], o[3]);
    }

    // block reduction: wave64 shuffle tree, then 4 wave sums via LDS
#pragma unroll
    for (int off = 32; off > 0; off >>= 1)
        gsum += __shfl_down(gsum, off, 64);
    __shared__ float wsum[4];
    int wid  = threadIdx.x >> 6;
    int lane = threadIdx.x & 63;
    if (lane == 0) wsum[wid] = gsum;
    __syncthreads();
    if (threadIdx.x == 0) {
        float s = wsum[0] + wsum[1] + wsum[2] + wsum[3];
        atomicAdd(&qt[b], s * (1.0f / (float)P));
    }
}

extern "C" void kernel_launch(void* const* d_in, const int* in_sizes, int n_in,
                              void* d_out, int out_size, void* d_ws, size_t ws_size,
                              hipStream_t stream) {
    const float* x     = (const float*)d_in[0];
    const float* W1    = (const float*)d_in[1];
    const float* b1    = (const float*)d_in[2];
    const float* W_ih  = (const float*)d_in[3];
    const float* b_ih  = (const float*)d_in[4];
    // d_in[5] = W_hh: unused (h0 = 0, only b_hh survives)
    const float* b_hh  = (const float*)d_in[6];
    const float* W_out = (const float*)d_in[7];
    const float* b_out = (const float*)d_in[8];
    const float* W_act = (const float*)d_in[9];
    const float* b_act = (const float*)d_in[10];

    int BP = in_sizes[0];          // B*P = 2097152
    int B  = out_size - BP;        // 64 (theta flat + qt)
    int P  = BP / B;               // 32768

    float* theta = (float*)d_out;
    float* qt    = theta + BP;

    // Table in workspace (float4 entries, 256 KB at 16384 points).
    int tblN = 16384;
    while ((size_t)tblN * sizeof(float4) > ws_size && tblN > 64) tblN >>= 1;
    float* tblf = (float*)d_ws;

    const float X0 = -10.0f, X1 = 10.0f;
    float dx = (X1 - X0) / (float)(tblN - 1);
    float inv_dx = 1.0f / dx;

    // qt region is re-poisoned before every launch; zero it (capturable memset node)
    hipMemsetAsync(qt, 0, B * sizeof(float), stream);

    int nblk = (tblN + PTS_PER_BLK - 1) / PTS_PER_BLK;
    build_table_kernel<<<nblk, 256, 0, stream>>>(
        W1, b1, W_ih, b_ih, b_hh, W_out, b_out, W_act, b_act, tblf, tblN, X0, dx);

    int chunks = P / 2048;
    eval_kernel<<<B * chunks, 256, 0, stream>>>(
        x, (const float4*)d_ws, theta, qt, tblN, X0, inv_dx, P, chunks);
}

// Round 3
// 93.585 us; speedup vs baseline: 1.3716x; 1.0405x over previous
//
#include <hip/hip_runtime.h>
#include <math.h>

#define HID 20
#define NGATE 80
#define NLAYER 2
#define PTS_PER_BLK 12   // 12 points x 20 gates = 240 active threads of 256
#define TBL_N 2048       // 32 KB float4 table; L1-resident for eval gathers

__device__ __forceinline__ float sigmoidf_(float v) { return 1.0f / (1.0f + expf(-v)); }

// Cooperative table build. Weights staged to LDS with COALESCED loads (the R2
// version read gate rows straight from global: 64 lanes stride-80B apart =
// fully divergent VMEM, ~tens of cycles of TA address processing per load —
// that was the hidden ~15us). Block 0 also zeroes qt (replaces the memset node).
// Table format: tbl4[i] = (F_i, G_i, F_{i+1}, G_{i+1}) -> eval does ONE 16B gather.
__global__ __launch_bounds__(256) void build_table_kernel(
    const float* __restrict__ W1, const float* __restrict__ b1,
    const float* __restrict__ W_ih, const float* __restrict__ b_ih,
    const float* __restrict__ b_hh,
    const float* __restrict__ W_out, const float* __restrict__ b_out,
    const float* __restrict__ W_act, const float* __restrict__ b_act,
    float* __restrict__ tblf, float* __restrict__ qt, int Bq,
    int tblN, float x0, float dx)
{
    __shared__ float sWf[NLAYER * NGATE * HID];  // 12.8 KB: full W_ih
    __shared__ float sBias[NLAYER * NGATE];      // 640 B: b_ih + b_hh combined
    __shared__ float sWo[2][HID];                // W_out, W_act
    __shared__ float sh[PTS_PER_BLK][HID];       // hidden state between layers

    int tid = threadIdx.x;

    // coalesced staging
    for (int idx = tid; idx < NLAYER * NGATE * HID; idx += 256) sWf[idx] = W_ih[idx];
    for (int idx = tid; idx < NLAYER * NGATE; idx += 256) sBias[idx] = b_ih[idx] + b_hh[idx];
    if (tid < HID) { sWo[0][tid] = W_out[tid]; sWo[1][tid] = W_act[tid]; }

    if (blockIdx.x == 0 && tid < Bq) qt[tid] = 0.0f;  // eval runs after us on stream

    bool active = tid < PTS_PER_BLK * HID;
    int p_local = tid / HID;        // 0..11
    int gi      = tid % HID;        // 0..19
    int i = blockIdx.x * PTS_PER_BLK + p_local;
    bool valid = active && (i < tblN);

    if (active) {
        float xv = x0 + dx * (float)i;
        sh[p_local][gi] = fmaf(xv, W1[gi], b1[gi]);
    }
    __syncthreads();

    float hval = 0.0f;
    for (int l = 0; l < NLAYER; ++l) {
        if (active) {
            const float* Wl = sWf + l * (NGATE * HID);
            const float* bs = sBias + l * NGATE;
            // torch gate order: i(0..19) f(20..39, dead: c0=0) g(40..59) o(60..79)
            float si = bs[gi];
            float sg = bs[HID * 2 + gi];
            float so = bs[HID * 3 + gi];
            const float* wi = Wl + gi * HID;
            const float* wg = Wl + (HID * 2 + gi) * HID;
            const float* wo = Wl + (HID * 3 + gi) * HID;
#pragma unroll
            for (int k = 0; k < HID; ++k) {
                float hk = sh[p_local][k];       // broadcast within p_local group
                si = fmaf(wi[k], hk, si);
                sg = fmaf(wg[k], hk, sg);
                so = fmaf(wo[k], hk, so);
            }
            float iv = sigmoidf_(si);
            float gv = tanhf(sg);
            float ov = sigmoidf_(so);
            hval = ov * tanhf(iv * gv);   // c = i*g (f*c0 == 0), h = o*tanh(c)
        }
        __syncthreads();
        if (active) sh[p_local][gi] = hval;
        __syncthreads();
    }

    // gi==0 -> theta dot, gi==1 -> act dot; duplicated-neighbor table layout
    if (valid && gi < 2) {
        float acc = (gi == 0) ? b_out[0] : b_act[0];
#pragma unroll
        for (int k = 0; k < HID; ++k) acc = fmaf(sh[p_local][k], sWo[gi][k], acc);
        tblf[4 * i + gi] = acc;                       // (F_i, G_i)
        if (i > 0) tblf[4 * (i - 1) + 2 + gi] = acc;  // (F_i, G_i) -> entry i-1 .zw
    }
}

// Memory-bound gather+lerp: theta[b,p] = lerp(F, x), qt[b] += mean(lerp(G, x)).
// Each block handles 2048 contiguous elements of one row (2 x float4 per thread).
__global__ __launch_bounds__(256) void eval_kernel(
    const float* __restrict__ x, const float4* __restrict__ tbl4,
    float* __restrict__ theta, float* __restrict__ qt,
    int tblN, float x0, float inv_dx, int P, int chunks_per_row)
{
    int b = blockIdx.x / chunks_per_row;
    int c = blockIdx.x % chunks_per_row;
    size_t base = (size_t)b * (size_t)P + (size_t)c * 2048;
    const float4* xin = (const float4*)(x + base);
    float4* tout = (float4*)(theta + base);

    float gsum = 0.0f;
    float tmax = (float)(tblN - 1);

#pragma unroll
    for (int j = 0; j < 2; ++j) {
        float4 xv = xin[j * 256 + threadIdx.x];
        float in[4] = {xv.x, xv.y, xv.z, xv.w};
        float o[4];
#pragma unroll
        for (int k = 0; k < 4; ++k) {
            float tt = (in[k] - x0) * inv_dx;
            tt = fminf(fmaxf(tt, 0.0f), tmax);
            int i0 = (int)tt;
            if (i0 > tblN - 2) i0 = tblN - 2;
            float fr = tt - (float)i0;
            float4 e = tbl4[i0];              // (F0, G0, F1, G1) — one 16B gather
            o[k]  = fmaf(fr, e.z - e.x, e.x);
            gsum += fmaf(fr, e.w - e.y, e.y);
        }
        tout[j * 256 + threadIdx.x] = make_float4(o[0], o[1], o[2], o[3]);
    }

    // block reduction: wave64 shuffle tree, then 4 wave sums via LDS
#pragma unroll
    for (int off = 32; off > 0; off >>= 1)
        gsum += __shfl_down(gsum, off, 64);
    __shared__ float wsum[4];
    int wid  = threadIdx.x >> 6;
    int lane = threadIdx.x & 63;
    if (lane == 0) wsum[wid] = gsum;
    __syncthreads();
    if (threadIdx.x == 0) {
        float s = wsum[0] + wsum[1] + wsum[2] + wsum[3];
        atomicAdd(&qt[b], s * (1.0f / (float)P));
    }
}

extern "C" void kernel_launch(void* const* d_in, const int* in_sizes, int n_in,
                              void* d_out, int out_size, void* d_ws, size_t ws_size,
                              hipStream_t stream) {
    const float* x     = (const float*)d_in[0];
    const float* W1    = (const float*)d_in[1];
    const float* b1    = (const float*)d_in[2];
    const float* W_ih  = (const float*)d_in[3];
    const float* b_ih  = (const float*)d_in[4];
    // d_in[5] = W_hh: unused (h0 = 0, only b_hh survives)
    const float* b_hh  = (const float*)d_in[6];
    const float* W_out = (const float*)d_in[7];
    const float* b_out = (const float*)d_in[8];
    const float* W_act = (const float*)d_in[9];
    const float* b_act = (const float*)d_in[10];

    int BP = in_sizes[0];          // B*P = 2097152
    int B  = out_size - BP;        // 64 (theta flat + qt)
    int P  = BP / B;               // 32768

    float* theta = (float*)d_out;
    float* qt    = theta + BP;

    int tblN = TBL_N;              // 32 KB float4 table in workspace
    while ((size_t)tblN * sizeof(float4) > ws_size && tblN > 64) tblN >>= 1;
    float* tblf = (float*)d_ws;

    const float X0 = -10.0f, X1 = 10.0f;
    float dx = (X1 - X0) / (float)(tblN - 1);
    float inv_dx = 1.0f / dx;

    int nblk = (tblN + PTS_PER_BLK - 1) / PTS_PER_BLK;
    build_table_kernel<<<nblk, 256, 0, stream>>>(
        W1, b1, W_ih, b_ih, b_hh, W_out, b_out, W_act, b_act,
        tblf, qt, B, tblN, X0, dx);

    int chunks = P / 2048;
    eval_kernel<<<B * chunks, 256, 0, stream>>>(
        x, (const float4*)d_ws, theta, qt, tblN, X0, inv_dx, P, chunks);
}

// Round 4
// 91.886 us; speedup vs baseline: 1.3969x; 1.0185x over previous
//
#include <hip/hip_runtime.h>
#include <math.h>

#define HID 20
#define NGATE 80
#define NLAYER 2
#define PTS_PER_BLK 12   // 12 points x 20 gates = 240 active threads of 256
#define TBL_N 2048       // 32 KB float4 table; staged to LDS in eval

__device__ __forceinline__ float sigmoidf_(float v) { return 1.0f / (1.0f + expf(-v)); }

// Cooperative table build; weights staged to LDS coalesced (R2's direct global
// gate-row reads were stride-80B divergent VMEM). Block 0 zeroes qt.
// Table format: tbl4[i] = (F_i, G_i, F_{i+1}, G_{i+1}) -> eval does ONE 16B read.
__global__ __launch_bounds__(256) void build_table_kernel(
    const float* __restrict__ W1, const float* __restrict__ b1,
    const float* __restrict__ W_ih, const float* __restrict__ b_ih,
    const float* __restrict__ b_hh,
    const float* __restrict__ W_out, const float* __restrict__ b_out,
    const float* __restrict__ W_act, const float* __restrict__ b_act,
    float* __restrict__ tblf, float* __restrict__ qt, int Bq,
    int tblN, float x0, float dx)
{
    __shared__ float sWf[NLAYER * NGATE * HID];  // 12.8 KB: full W_ih
    __shared__ float sBias[NLAYER * NGATE];      // 640 B: b_ih + b_hh combined
    __shared__ float sWo[2][HID];                // W_out, W_act
    __shared__ float sh[PTS_PER_BLK][HID];       // hidden state between layers

    int tid = threadIdx.x;

    for (int idx = tid; idx < NLAYER * NGATE * HID; idx += 256) sWf[idx] = W_ih[idx];
    for (int idx = tid; idx < NLAYER * NGATE; idx += 256) sBias[idx] = b_ih[idx] + b_hh[idx];
    if (tid < HID) { sWo[0][tid] = W_out[tid]; sWo[1][tid] = W_act[tid]; }

    if (blockIdx.x == 0 && tid < Bq) qt[tid] = 0.0f;  // eval runs after us on stream

    bool active = tid < PTS_PER_BLK * HID;
    int p_local = tid / HID;        // 0..11
    int gi      = tid % HID;        // 0..19
    int i = blockIdx.x * PTS_PER_BLK + p_local;
    bool valid = active && (i < tblN);

    if (active) {
        float xv = x0 + dx * (float)i;
        sh[p_local][gi] = fmaf(xv, W1[gi], b1[gi]);
    }
    __syncthreads();

    float hval = 0.0f;
    for (int l = 0; l < NLAYER; ++l) {
        if (active) {
            const float* Wl = sWf + l * (NGATE * HID);
            const float* bs = sBias + l * NGATE;
            // torch gate order: i(0..19) f(20..39, dead: c0=0) g(40..59) o(60..79)
            float si = bs[gi];
            float sg = bs[HID * 2 + gi];
            float so = bs[HID * 3 + gi];
            const float* wi = Wl + gi * HID;
            const float* wg = Wl + (HID * 2 + gi) * HID;
            const float* wo = Wl + (HID * 3 + gi) * HID;
#pragma unroll
            for (int k = 0; k < HID; ++k) {
                float hk = sh[p_local][k];
                si = fmaf(wi[k], hk, si);
                sg = fmaf(wg[k], hk, sg);
                so = fmaf(wo[k], hk, so);
            }
            float iv = sigmoidf_(si);
            float gv = tanhf(sg);
            float ov = sigmoidf_(so);
            hval = ov * tanhf(iv * gv);   // c = i*g (f*c0 == 0), h = o*tanh(c)
        }
        __syncthreads();
        if (active) sh[p_local][gi] = hval;
        __syncthreads();
    }

    if (valid && gi < 2) {
        float acc = (gi == 0) ? b_out[0] : b_act[0];
#pragma unroll
        for (int k = 0; k < HID; ++k) acc = fmaf(sh[p_local][k], sWo[gi][k], acc);
        tblf[4 * i + gi] = acc;                       // (F_i, G_i)
        if (i > 0) tblf[4 * (i - 1) + 2 + gi] = acc;  // (F_i, G_i) -> entry i-1 .zw
    }
}

// Gather+lerp with the table in LDS: global gathers were address-divergent
// (up to 64 TA transactions/instr); random ds_read_b128 averages ~2x the
// 12-cyc baseline instead. Staging is 8 coalesced float4 per thread (L2-hot).
__global__ __launch_bounds__(256) void eval_kernel(
    const float* __restrict__ x, const float4* __restrict__ tbl4,
    float* __restrict__ theta, float* __restrict__ qt,
    int tblN, float x0, float inv_dx, int P, int chunks_per_row)
{
    __shared__ float4 stbl[TBL_N];               // 32 KB -> 4-5 blocks/CU
    for (int idx = threadIdx.x; idx < tblN; idx += 256) stbl[idx] = tbl4[idx];
    __syncthreads();

    int b = blockIdx.x / chunks_per_row;
    int c = blockIdx.x % chunks_per_row;
    size_t base = (size_t)b * (size_t)P + (size_t)c * 2048;
    const float4* xin = (const float4*)(x + base);
    float4* tout = (float4*)(theta + base);

    float gsum = 0.0f;
    float tmax = (float)(tblN - 1);

#pragma unroll
    for (int j = 0; j < 2; ++j) {
        float4 xv = xin[j * 256 + threadIdx.x];
        float in[4] = {xv.x, xv.y, xv.z, xv.w};
        float o[4];
#pragma unroll
        for (int k = 0; k < 4; ++k) {
            float tt = (in[k] - x0) * inv_dx;
            tt = fminf(fmaxf(tt, 0.0f), tmax);
            int i0 = (int)tt;
            if (i0 > tblN - 2) i0 = tblN - 2;
            float fr = tt - (float)i0;
            float4 e = stbl[i0];              // (F0, G0, F1, G1) — one LDS b128
            o[k]  = fmaf(fr, e.z - e.x, e.x);
            gsum += fmaf(fr, e.w - e.y, e.y);
        }
        tout[j * 256 + threadIdx.x] = make_float4(o[0], o[1], o[2], o[3]);
    }

    // block reduction: wave64 shuffle tree, then 4 wave sums via LDS
#pragma unroll
    for (int off = 32; off > 0; off >>= 1)
        gsum += __shfl_down(gsum, off, 64);
    __shared__ float wsum[4];
    int wid  = threadIdx.x >> 6;
    int lane = threadIdx.x & 63;
    if (lane == 0) wsum[wid] = gsum;
    __syncthreads();
    if (threadIdx.x == 0) {
        float s = wsum[0] + wsum[1] + wsum[2] + wsum[3];
        atomicAdd(&qt[b], s * (1.0f / (float)P));
    }
}

extern "C" void kernel_launch(void* const* d_in, const int* in_sizes, int n_in,
                              void* d_out, int out_size, void* d_ws, size_t ws_size,
                              hipStream_t stream) {
    const float* x     = (const float*)d_in[0];
    const float* W1    = (const float*)d_in[1];
    const float* b1    = (const float*)d_in[2];
    const float* W_ih  = (const float*)d_in[3];
    const float* b_ih  = (const float*)d_in[4];
    // d_in[5] = W_hh: unused (h0 = 0, only b_hh survives)
    const float* b_hh  = (const float*)d_in[6];
    const float* W_out = (const float*)d_in[7];
    const float* b_out = (const float*)d_in[8];
    const float* W_act = (const float*)d_in[9];
    const float* b_act = (const float*)d_in[10];

    int BP = in_sizes[0];          // B*P = 2097152
    int B  = out_size - BP;        // 64 (theta flat + qt)
    int P  = BP / B;               // 32768

    float* theta = (float*)d_out;
    float* qt    = theta + BP;

    int tblN = TBL_N;              // 32 KB float4 table in workspace
    while ((size_t)tblN * sizeof(float4) > ws_size && tblN > 64) tblN >>= 1;
    float* tblf = (float*)d_ws;

    const float X0 = -10.0f, X1 = 10.0f;
    float dx = (X1 - X0) / (float)(tblN - 1);
    float inv_dx = 1.0f / dx;

    int nblk = (tblN + PTS_PER_BLK - 1) / PTS_PER_BLK;
    build_table_kernel<<<nblk, 256, 0, stream>>>(
        W1, b1, W_ih, b_ih, b_hh, W_out, b_out, W_act, b_act,
        tblf, qt, B, tblN, X0, dx);

    int chunks = P / 2048;
    eval_kernel<<<B * chunks, 256, 0, stream>>>(
        x, (const float4*)d_ws, theta, qt, tblN, X0, inv_dx, P, chunks);
}